// Round 5
// baseline (199.830 us; speedup 1.0000x reference)
//
#include <hip/hip_runtime.h>
#include <hip/hip_bf16.h>

typedef __attribute__((ext_vector_type(8))) short short8;
typedef __attribute__((ext_vector_type(4))) float floatx4;
typedef __attribute__((ext_vector_type(4))) int intx4;

#define D_MODEL 1024
#define SEQ     2048
#define NB      2
#define NH      16
#define HD      64
#define MROWS   4096   // NB*SEQ
#define CZ      (0.125f * 1.44269504f)   // 1/sqrt(64) * log2(e)

__device__ __forceinline__ floatx4 mfma_bf16(short8 a, short8 b, floatx4 c) {
  return __builtin_amdgcn_mfma_f32_16x16x32_bf16(a, b, c, 0, 0, 0);
}

// async global -> LDS, 16 B per lane. LDS dest = wave-uniform base + lane*16.
__device__ __forceinline__ void dma16(const __hip_bfloat16* g, __hip_bfloat16* l) {
  __builtin_amdgcn_global_load_lds(
      (const __attribute__((address_space(1))) void*)g,
      (__attribute__((address_space(3))) void*)l, 16, 0, 0);
}
#define WAIT_VM(n)  __asm__ __volatile__("s_waitcnt vmcnt(" #n ")" ::: "memory")
#define BARRIER()   __asm__ __volatile__("s_barrier" ::: "memory")

__device__ __forceinline__ int packbf(float a, float b) {
  union { __hip_bfloat16 h; unsigned short u; } x, y;
  x.h = __float2bfloat16(a); y.h = __float2bfloat16(b);
  return (int)(((unsigned)y.u << 16) | (unsigned)x.u);
}

// ---------------- x fp32 -> bf16 ----------------
__global__ void convert_x_kernel(const float* __restrict__ x, __hip_bfloat16* __restrict__ xb) {
  int i = (blockIdx.x * 256 + threadIdx.x) * 4;
  float4 v = *(const float4*)(x + i);
  __hip_bfloat16 tmp[4];
  tmp[0] = __float2bfloat16(v.x);
  tmp[1] = __float2bfloat16(v.y);
  tmp[2] = __float2bfloat16(v.z);
  tmp[3] = __float2bfloat16(v.w);
  *(ushort4*)(xb + i) = *(ushort4*)tmp;
}

// ---------------- W [K][N] fp32 -> Wt [N][K] bf16, 4 matrices via blockIdx.z ----------------
__global__ void transpose_w_kernel(const float* __restrict__ W0, const float* __restrict__ W1,
                                   const float* __restrict__ W2, const float* __restrict__ W3,
                                   __hip_bfloat16* __restrict__ T0, __hip_bfloat16* __restrict__ T1,
                                   __hip_bfloat16* __restrict__ T2, __hip_bfloat16* __restrict__ T3) {
  const int z = blockIdx.z;
  const float* W = (z == 0) ? W0 : (z == 1) ? W1 : (z == 2) ? W2 : W3;
  __hip_bfloat16* Wt = (z == 0) ? T0 : (z == 1) ? T1 : (z == 2) ? T2 : T3;
  __shared__ float tile[32][33];
  int k0 = blockIdx.x * 32, n0 = blockIdx.y * 32;
  int tx = threadIdx.x, ty = threadIdx.y;  // block (32,8)
#pragma unroll
  for (int i = 0; i < 4; i++)
    tile[ty + 8 * i][tx] = W[(size_t)(k0 + ty + 8 * i) * D_MODEL + n0 + tx];
  __syncthreads();
#pragma unroll
  for (int i = 0; i < 4; i++)
    Wt[(size_t)(n0 + ty + 8 * i) * D_MODEL + k0 + tx] = __float2bfloat16(tile[tx][ty + 8 * i]);
}

// ---------------- GEMM: Y = (X @ W + b) * scale ----------------
// Triple-buffered LDS, raw s_barrier + fine-grained vmcnt (never 0 mid-loop).
// MODE 0: MT=128; grid (8 n, 3 z, 32 m). z=0 -> Q bf16 [bh][s][d] * CZ;
//         z=1 -> K bf16 [bh][s][d]; z=2 -> V^T bf16 [bh][d][s].
// MODE 1: MT=64; grid (8 n, 1, 64 m). fp32 row-major out.
template <int MODE>
__global__ __launch_bounds__(256) void gemm_kernel(
    const __hip_bfloat16* __restrict__ X,
    const __hip_bfloat16* __restrict__ Wt0, const __hip_bfloat16* __restrict__ Wt1,
    const __hip_bfloat16* __restrict__ Wt2,
    const float* __restrict__ b0, const float* __restrict__ b1, const float* __restrict__ b2,
    void* __restrict__ out0, void* __restrict__ out1, void* __restrict__ out2) {
  constexpr int MT = (MODE == 0) ? 128 : 64;
  constexpr int I = MT / 32;        // acc row-frags per wave
  constexpr int NKT = D_MODEL / 32; // 32 k-iterations

  const int z = blockIdx.y;
  const __hip_bfloat16* Wt = (z == 0) ? Wt0 : (z == 1) ? Wt1 : Wt2;
  const float* bias = (z == 0) ? b0 : (z == 1) ? b1 : b2;
  void* outp = (z == 0) ? out0 : (z == 1) ? out1 : out2;
  const float scale = (MODE == 0 && z == 0) ? CZ : 1.f;

  __shared__ __attribute__((aligned(16))) __hip_bfloat16 As[3][MT * 32];
  __shared__ __attribute__((aligned(16))) __hip_bfloat16 Bs[3][128 * 32];

  const int n0 = blockIdx.x * 128;
  const int m0 = blockIdx.z * MT;
  const int t = threadIdx.x;
  const int lane = t & 63, w = t >> 6;
  const int wm = (w >> 1) * (MT / 2), wn = (w & 1) * 64;
  const int lr = lane & 15;
  const int lq = lane >> 4;

  const __hip_bfloat16* Xp = X + (size_t)m0 * D_MODEL;
  const __hip_bfloat16* Wp = Wt + (size_t)n0 * D_MODEL;

  const int lrow = lane >> 2;               // 0..15 within a 16-row dma inst
  const int skg = (lane & 3) << 3;          // k-offset elems
  const int srowA = ((MT == 128) ? (w << 5) : (w << 4)) + lrow;
  const int sbA0 = (((MT == 128) ? (w << 5) : (w << 4)) << 5);
  const int sbA1 = sbA0 + (16 << 5);
  const int srowB = (w << 5) + lrow;
  const int sbB0 = ((w << 5) << 5);
  const int sbB1 = sbB0 + (16 << 5);

#define STAGE_G(kt_, buf_)                                                              \
  {                                                                                     \
    const int kn_ = (kt_) * 32;                                                         \
    dma16(Xp + (size_t)srowA * D_MODEL + kn_ + skg, &As[buf_][sbA0]);                   \
    if (MT == 128) dma16(Xp + (size_t)(srowA + 16) * D_MODEL + kn_ + skg, &As[buf_][sbA1]); \
    dma16(Wp + (size_t)srowB * D_MODEL + kn_ + skg, &Bs[buf_][sbB0]);                   \
    dma16(Wp + (size_t)(srowB + 16) * D_MODEL + kn_ + skg, &Bs[buf_][sbB1]);            \
  }

  floatx4 acc[I][4];
#pragma unroll
  for (int i = 0; i < I; i++)
#pragma unroll
    for (int j = 0; j < 4; j++) acc[i][j] = (floatx4){0.f, 0.f, 0.f, 0.f};

  STAGE_G(0, 0);
  STAGE_G(1, 1);

  int cb = 0;
  for (int kt = 0; kt < NKT; kt++) {
    if (kt < NKT - 1) {
      if constexpr (MODE == 0) WAIT_VM(4);
      else                     WAIT_VM(3);
    } else {
      WAIT_VM(0);
    }
    BARRIER();
    if (kt + 2 < NKT) {
      const int nb = (cb == 0) ? 2 : cb - 1;  // (kt+2)%3
      STAGE_G(kt + 2, nb);
    }
    const __hip_bfloat16* Ac = As[cb];
    const __hip_bfloat16* Bc = Bs[cb];
    short8 af[I], bfr[4];
#pragma unroll
    for (int i = 0; i < I; i++) af[i] = *(const short8*)&Ac[(wm + i * 16 + lr) * 32 + lq * 8];
#pragma unroll
    for (int j = 0; j < 4; j++) bfr[j] = *(const short8*)&Bc[(wn + j * 16 + lr) * 32 + lq * 8];
#pragma unroll
    for (int i = 0; i < I; i++)
#pragma unroll
      for (int j = 0; j < 4; j++) acc[i][j] = mfma_bf16(af[i], bfr[j], acc[i][j]);
    cb = (cb == 2) ? 0 : cb + 1;
  }
#undef STAGE_G

#pragma unroll
  for (int j = 0; j < 4; j++) {
    const int n = n0 + wn + j * 16 + lr;
    const float bv = bias[n];
#pragma unroll
    for (int i = 0; i < I; i++) {
      const int mb = m0 + wm + i * 16 + lq * 4;  // first of 4 consecutive rows
      if (MODE == 0) {
        __hip_bfloat16* O = (__hip_bfloat16*)outp;
        const int b = mb >> 11, s = mb & 2047;
        const int h = n >> 6, d = n & 63;
        if (z == 2) {
          ushort4 pk;
          __hip_bfloat16* pp = (__hip_bfloat16*)&pk;
#pragma unroll
          for (int r = 0; r < 4; r++) pp[r] = __float2bfloat16(acc[i][j][r] + bv);
          *(ushort4*)(O + (((size_t)(b * NH + h) * HD + d) * SEQ + s)) = pk;
        } else {
#pragma unroll
          for (int r = 0; r < 4; r++)
            O[(((size_t)(b * NH + h) * SEQ + (s + r)) * HD) + d] =
                __float2bfloat16((acc[i][j][r] + bv) * scale);
        }
      } else {
#pragma unroll
        for (int r = 0; r < 4; r++)
          ((float*)outp)[(size_t)(mb + r) * D_MODEL + n] = acc[i][j][r] + bv;
      }
    }
  }
}

// ---------------- flash attention, causal, no-max softmax, S^T + key-split ----------------
// Grid (32 bh, 16 p), 512 threads (8 waves). XCD: linear%8 = bh%8 -> one XCD per bh group.
// Waves: wr = w&3 -> 16-row group; wb = w>>2 -> key half (64 keys) of a 128-key tile.
// Block does Q-tiles p and 31-p (64 rows each) -> uniform 17 K-tile iterations.
// S^T orientation: one query per lane; P -> PV B-operand via ds_bpermute (no LDS round-trip).
__global__ __launch_bounds__(512, 4) void attn_kernel(
    const __hip_bfloat16* __restrict__ Q, const __hip_bfloat16* __restrict__ Kg,
    const __hip_bfloat16* __restrict__ Vt, __hip_bfloat16* __restrict__ ctx) {
  const int bh = blockIdx.x;
  const int b = bh >> 4, h = bh & 15;
  const int p = blockIdx.y;  // 0..15
  const int t = threadIdx.x, lane = t & 63, w = t >> 6;
  const int lr = lane & 15, lq = lane >> 4;
  const int wr = w & 3, wb = w >> 2;

  __shared__ __attribute__((aligned(16))) __hip_bfloat16 Ks[2][128 * 64];   // [key][d] swz
  __shared__ __attribute__((aligned(16))) __hip_bfloat16 VTs[2][64 * 128];  // [d][key] swz

  const __hip_bfloat16* Qb = Q + (size_t)bh * SEQ * HD;
  const __hip_bfloat16* Kb = Kg + (size_t)bh * SEQ * HD;
  const __hip_bfloat16* Vb = Vt + (size_t)bh * HD * SEQ;

  // Q fragments for both phases (plain global loads, before any DMA)
  short8 qf[2][2];
#pragma unroll
  for (int ph = 0; ph < 2; ph++) {
    const int qt = ph ? 31 - p : p;
    const int rw = qt * 64 + wr * 16;
#pragma unroll
    for (int ks = 0; ks < 2; ks++)
      qf[ph][ks] = *(const short8*)(Qb + (size_t)(rw + lr) * HD + ks * 32 + lq * 8);
  }

  // staging lane constants
  const int kr0 = (w << 4) + (lane >> 3);           // K row (+n0), 3-bit XOR swz
  const int kg0 = (lane & 7) ^ (kr0 & 7);
  const int kr1 = kr0 + 8;
  const int kg1 = (lane & 7) ^ (kr1 & 7);
  const int kb0 = (w << 4) << 6;
  const int kb1 = ((w << 4) + 8) << 6;
  const int vr0 = (w << 3) + (lane >> 4);           // V^T row d, 4-bit XOR swz
  const int vg0 = (lane & 15) ^ (vr0 & 15);
  const int vr1 = vr0 + 4;
  const int vg1 = (lane & 15) ^ (vr1 & 15);
  const int vb0 = (w << 3) << 7;
  const int vb1 = ((w << 3) + 4) << 7;

  const int nktA = (p + 2) >> 1;
  const int TOT = 17;

#define STAGE(nn, nb)                                                           \
  {                                                                             \
    dma16(Kb + ((size_t)((nn) + kr0) << 6) + (kg0 << 3), &Ks[nb][kb0]);         \
    dma16(Kb + ((size_t)((nn) + kr1) << 6) + (kg1 << 3), &Ks[nb][kb1]);         \
    dma16(Vb + (size_t)vr0 * SEQ + (nn) + (vg0 << 3), &VTs[nb][vb0]);           \
    dma16(Vb + (size_t)vr1 * SEQ + (nn) + (vg1 << 3), &VTs[nb][vb1]);           \
  }

  STAGE(0, 0);
  int g = 0;

  const int idx0 = (lr + ((lq & 1) << 5)) << 2;  // bpermute byte index
  const int idx1 = idx0 + 64;
  const bool hi = (lq >= 2);

  for (int ph = 0; ph < 2; ph++) {
    const int qt = ph ? 31 - p : p;
    const int nkt = (qt + 2) >> 1;
    const int rw = qt * 64 + wr * 16;
    const int q = rw + lr;  // this lane's query row

    floatx4 o[4];
#pragma unroll
    for (int dt = 0; dt < 4; dt++) o[dt] = (floatx4){0.f, 0.f, 0.f, 0.f};
    float ls = 0.f;

    for (int kt = 0; kt < nkt; kt++, g++) {
      WAIT_VM(0);
      BARRIER();
      if (g + 1 < TOT) {
        const int gn = g + 1;
        const int ktn = (gn < nktA) ? gn : gn - nktA;
        STAGE(ktn << 7, gn & 1);
      }
      const int n0 = (kt << 7) + (wb << 6);  // this wave's 64-key window
      if (n0 <= rw + 15) {
        const __hip_bfloat16* Kc = Ks[g & 1];
        const __hip_bfloat16* Vc = VTs[g & 1];

        // S^T = K Q^T : A = K-frag (m=key), B = Q-frag (n=query)
        floatx4 s[4];
#pragma unroll
        for (int nt = 0; nt < 4; nt++) s[nt] = (floatx4){0.f, 0.f, 0.f, 0.f};
#pragma unroll
        for (int ks = 0; ks < 2; ks++) {
#pragma unroll
          for (int nt = 0; nt < 4; nt++) {
            const int row = (wb << 6) + (nt << 4) + lr;
            short8 kf = *(const short8*)&Kc[(row << 6) + ((((ks << 2) + lq) ^ (row & 7)) << 3)];
            s[nt] = mfma_bf16(kf, qf[ph][ks], s[nt]);
          }
        }

        // softmax numerators; lane (lr,lq) reg r holds key n0+16nt+4lq+r, query q
        int pkA[4], pkB[4];
        if (n0 + 63 > rw) {  // diagonal region: mask
#pragma unroll
          for (int nt = 0; nt < 4; nt++) {
            const int kbase = n0 + (nt << 4) + (lq << 2);
            float pe[4];
#pragma unroll
            for (int r = 0; r < 4; r++) {
              pe[r] = (kbase + r <= q) ? exp2f(s[nt][r]) : 0.f;
              ls += pe[r];
            }
            pkA[nt] = packbf(pe[0], pe[1]);
            pkB[nt] = packbf(pe[2], pe[3]);
          }
        } else {
#pragma unroll
          for (int nt = 0; nt < 4; nt++) {
            float pe[4];
#pragma unroll
            for (int r = 0; r < 4; r++) {
              pe[r] = exp2f(s[nt][r]);
              ls += pe[r];
            }
            pkA[nt] = packbf(pe[0], pe[1]);
            pkB[nt] = packbf(pe[2], pe[3]);
          }
        }

        // build P^T B-frags via bpermute and accumulate O^T = V^T P^T
#pragma unroll
        for (int ks = 0; ks < 2; ks++) {
          const int t0 = 2 * ks, t1 = 2 * ks + 1;
          int c0a = __builtin_amdgcn_ds_bpermute(idx0, pkA[t0]);
          int c0b = __builtin_amdgcn_ds_bpermute(idx0, pkA[t1]);
          int c1a = __builtin_amdgcn_ds_bpermute(idx0, pkB[t0]);
          int c1b = __builtin_amdgcn_ds_bpermute(idx0, pkB[t1]);
          int c2a = __builtin_amdgcn_ds_bpermute(idx1, pkA[t0]);
          int c2b = __builtin_amdgcn_ds_bpermute(idx1, pkA[t1]);
          int c3a = __builtin_amdgcn_ds_bpermute(idx1, pkB[t0]);
          int c3b = __builtin_amdgcn_ds_bpermute(idx1, pkB[t1]);
          intx4 bi;
          bi[0] = hi ? c0b : c0a;
          bi[1] = hi ? c1b : c1a;
          bi[2] = hi ? c2b : c2a;
          bi[3] = hi ? c3b : c3a;
          short8 pf = __builtin_bit_cast(short8, bi);
#pragma unroll
          for (int dt = 0; dt < 4; dt++) {
            const int row = (dt << 4) + lr;
            const int gv = (wb << 3) + (ks << 2) + lq;
            short8 vf = *(const short8*)&Vc[(row << 7) + ((gv ^ (row & 15)) << 3)];
            o[dt] = mfma_bf16(vf, pf, o[dt]);
          }
        }
      }
    }

    // phase epilogue: combine key-split partials, normalize, write ctx
    const int fb = (g - 1) & 1;  // buffer free after the barrier below
    BARRIER();
    {
      float* od = (float*)&Ks[fb][0];
      float* ld = (float*)&VTs[fb][0];
      const int base = (wr << 10) + (lane << 4);
      if (wb == 1) {
#pragma unroll
        for (int dt = 0; dt < 4; dt++) *(floatx4*)&od[base + (dt << 2)] = o[dt];
        ld[(wr << 6) + lane] = ls;
      }
      BARRIER();
      if (wb == 0) {
#pragma unroll
        for (int dt = 0; dt < 4; dt++) o[dt] += *(const floatx4*)&od[base + (dt << 2)];
        ls += ld[(wr << 6) + lane];
        ls += __shfl_xor(ls, 16);
        ls += __shfl_xor(ls, 32);
        const float inv = 1.f / ls;
        __hip_bfloat16* cp = ctx + (size_t)b * SEQ * D_MODEL + h * HD + (size_t)q * D_MODEL;
#pragma unroll
        for (int dt = 0; dt < 4; dt++) {
          ushort4 pk;
          __hip_bfloat16* pp = (__hip_bfloat16*)&pk;
#pragma unroll
          for (int r = 0; r < 4; r++) pp[r] = __float2bfloat16(o[dt][r] * inv);
          *(ushort4*)(cp + (dt << 4) + (lq << 2)) = pk;
        }
      }
    }
    // next loop-top barrier protects the dump buffer before it is re-staged
  }
#undef STAGE
}

extern "C" void kernel_launch(void* const* d_in, const int* in_sizes, int n_in,
                              void* d_out, int out_size, void* d_ws, size_t ws_size,
                              hipStream_t stream) {
  const float* x  = (const float*)d_in[0];
  const float* Wq = (const float*)d_in[1];
  const float* bq = (const float*)d_in[2];
  const float* Wk = (const float*)d_in[3];
  const float* bk = (const float*)d_in[4];
  const float* Wv = (const float*)d_in[5];
  const float* bv = (const float*)d_in[6];
  const float* Wo = (const float*)d_in[7];
  const float* bo = (const float*)d_in[8];

  char* ws = (char*)d_ws;
  const size_t MB = 1u << 20;
  __hip_bfloat16* xb  = (__hip_bfloat16*)(ws + 0 * MB);   // 8 MB; reused as ctx after QKV GEMM
  __hip_bfloat16* wtq = (__hip_bfloat16*)(ws + 8 * MB);
  __hip_bfloat16* wtk = (__hip_bfloat16*)(ws + 10 * MB);
  __hip_bfloat16* wtv = (__hip_bfloat16*)(ws + 12 * MB);
  __hip_bfloat16* wto = (__hip_bfloat16*)(ws + 14 * MB);
  __hip_bfloat16* qb  = (__hip_bfloat16*)(ws + 16 * MB);
  __hip_bfloat16* kb  = (__hip_bfloat16*)(ws + 24 * MB);
  __hip_bfloat16* vt  = (__hip_bfloat16*)(ws + 32 * MB);
  __hip_bfloat16* ctx = xb;  // alias: x no longer needed after QKV projection

  convert_x_kernel<<<4096, 256, 0, stream>>>(x, xb);
  transpose_w_kernel<<<dim3(32, 32, 4), dim3(32, 8), 0, stream>>>(Wq, Wk, Wv, Wo,
                                                                  wtq, wtk, wtv, wto);
  gemm_kernel<0><<<dim3(8, 3, 32), 256, 0, stream>>>(xb, wtq, wtk, wtv, bq, bk, bv,
                                                     (void*)qb, (void*)kb, (void*)vt);
  attn_kernel<<<dim3(32, 16), 512, 0, stream>>>(qb, kb, vt, ctx);
  gemm_kernel<1><<<dim3(8, 1, 64), 256, 0, stream>>>(ctx, wto, wto, wto, bo, bo, bo,
                                                     d_out, d_out, d_out);
}

// Round 6
// 194.604 us; speedup vs baseline: 1.0269x; 1.0269x over previous
//
#include <hip/hip_runtime.h>
#include <hip/hip_bf16.h>

typedef __attribute__((ext_vector_type(8))) short short8;
typedef __attribute__((ext_vector_type(4))) float floatx4;
typedef __attribute__((ext_vector_type(4))) int intx4;

#define D_MODEL 1024
#define SEQ     2048
#define NB      2
#define NH      16
#define HD      64
#define MROWS   4096   // NB*SEQ
#define CZ      (0.125f * 1.44269504f)   // 1/sqrt(64) * log2(e)

__device__ __forceinline__ floatx4 mfma_bf16(short8 a, short8 b, floatx4 c) {
  return __builtin_amdgcn_mfma_f32_16x16x32_bf16(a, b, c, 0, 0, 0);
}

// async global -> LDS, 16 B per lane. LDS dest = wave-uniform base + lane*16.
__device__ __forceinline__ void dma16(const __hip_bfloat16* g, __hip_bfloat16* l) {
  __builtin_amdgcn_global_load_lds(
      (const __attribute__((address_space(1))) void*)g,
      (__attribute__((address_space(3))) void*)l, 16, 0, 0);
}
#define WAIT_VM(n)  __asm__ __volatile__("s_waitcnt vmcnt(" #n ")" ::: "memory")
#define BARRIER()   __asm__ __volatile__("s_barrier" ::: "memory")
#define WAIT_LGKM() __asm__ __volatile__("s_waitcnt lgkmcnt(0)" ::: "memory")

// round-half-up bf16 pair pack: (hi16(b+0x8000) << 16) | hi16(a+0x8000)
__device__ __forceinline__ int pack2bf(float a, float b) {
  unsigned ua = __builtin_bit_cast(unsigned, a) + 0x8000u;
  unsigned ub = __builtin_bit_cast(unsigned, b) + 0x8000u;
  return (int)__builtin_amdgcn_perm(ub, ua, 0x07060302u);
}

// ---------------- prep: W transpose (z<4) + x fp32->bf16 (z==4) ----------------
__global__ void prep_kernel(const float* __restrict__ x, __hip_bfloat16* __restrict__ xb,
                            const float* __restrict__ W0, const float* __restrict__ W1,
                            const float* __restrict__ W2, const float* __restrict__ W3,
                            __hip_bfloat16* __restrict__ T0, __hip_bfloat16* __restrict__ T1,
                            __hip_bfloat16* __restrict__ T2, __hip_bfloat16* __restrict__ T3) {
  const int z = blockIdx.z;
  if (z == 4) {
    const int tid = threadIdx.y * 32 + threadIdx.x;
    const int base = ((blockIdx.y * 32 + blockIdx.x) * 256 + tid) * 16;
#pragma unroll
    for (int c = 0; c < 4; c++) {
      float4 v = *(const float4*)(x + base + c * 4);
      __hip_bfloat16 tmp[4];
      tmp[0] = __float2bfloat16(v.x);
      tmp[1] = __float2bfloat16(v.y);
      tmp[2] = __float2bfloat16(v.z);
      tmp[3] = __float2bfloat16(v.w);
      *(ushort4*)(xb + base + c * 4) = *(ushort4*)tmp;
    }
    return;
  }
  const float* W = (z == 0) ? W0 : (z == 1) ? W1 : (z == 2) ? W2 : W3;
  __hip_bfloat16* Wt = (z == 0) ? T0 : (z == 1) ? T1 : (z == 2) ? T2 : T3;
  __shared__ float tile[32][33];
  int k0 = blockIdx.x * 32, n0 = blockIdx.y * 32;
  int tx = threadIdx.x, ty = threadIdx.y;  // block (32,8)
#pragma unroll
  for (int i = 0; i < 4; i++)
    tile[ty + 8 * i][tx] = W[(size_t)(k0 + ty + 8 * i) * D_MODEL + n0 + tx];
  __syncthreads();
#pragma unroll
  for (int i = 0; i < 4; i++)
    Wt[(size_t)(n0 + ty + 8 * i) * D_MODEL + k0 + tx] = __float2bfloat16(tile[tx][ty + 8 * i]);
}

// ---------------- GEMM: Y = (X @ W + b) * scale ----------------
// Triple-buffered LDS, raw s_barrier + fine-grained vmcnt (never 0 mid-loop).
// MODE 0: MT=128; grid (8 n, 3 z, 32 m). z=0 -> Q bf16 [bh][s][d] * CZ;
//         z=1 -> K bf16 [bh][s][d]; z=2 -> V^T bf16 [bh][d][s].
// MODE 1: MT=64; grid (8 n, 1, 64 m). fp32 row-major out.
template <int MODE>
__global__ __launch_bounds__(256) void gemm_kernel(
    const __hip_bfloat16* __restrict__ X,
    const __hip_bfloat16* __restrict__ Wt0, const __hip_bfloat16* __restrict__ Wt1,
    const __hip_bfloat16* __restrict__ Wt2,
    const float* __restrict__ b0, const float* __restrict__ b1, const float* __restrict__ b2,
    void* __restrict__ out0, void* __restrict__ out1, void* __restrict__ out2) {
  constexpr int MT = (MODE == 0) ? 128 : 64;
  constexpr int I = MT / 32;
  constexpr int NKT = D_MODEL / 32;

  const int z = blockIdx.y;
  const __hip_bfloat16* Wt = (z == 0) ? Wt0 : (z == 1) ? Wt1 : Wt2;
  const float* bias = (z == 0) ? b0 : (z == 1) ? b1 : b2;
  void* outp = (z == 0) ? out0 : (z == 1) ? out1 : out2;
  const float scale = (MODE == 0 && z == 0) ? CZ : 1.f;

  __shared__ __attribute__((aligned(16))) __hip_bfloat16 As[3][MT * 32];
  __shared__ __attribute__((aligned(16))) __hip_bfloat16 Bs[3][128 * 32];

  const int n0 = blockIdx.x * 128;
  const int m0 = blockIdx.z * MT;
  const int t = threadIdx.x;
  const int lane = t & 63, w = t >> 6;
  const int wm = (w >> 1) * (MT / 2), wn = (w & 1) * 64;
  const int lr = lane & 15;
  const int lq = lane >> 4;

  const __hip_bfloat16* Xp = X + (size_t)m0 * D_MODEL;
  const __hip_bfloat16* Wp = Wt + (size_t)n0 * D_MODEL;

  const int lrow = lane >> 2;
  const int skg = (lane & 3) << 3;
  const int srowA = ((MT == 128) ? (w << 5) : (w << 4)) + lrow;
  const int sbA0 = (((MT == 128) ? (w << 5) : (w << 4)) << 5);
  const int sbA1 = sbA0 + (16 << 5);
  const int srowB = (w << 5) + lrow;
  const int sbB0 = ((w << 5) << 5);
  const int sbB1 = sbB0 + (16 << 5);

#define STAGE_G(kt_, buf_)                                                              \
  {                                                                                     \
    const int kn_ = (kt_) * 32;                                                         \
    dma16(Xp + (size_t)srowA * D_MODEL + kn_ + skg, &As[buf_][sbA0]);                   \
    if (MT == 128) dma16(Xp + (size_t)(srowA + 16) * D_MODEL + kn_ + skg, &As[buf_][sbA1]); \
    dma16(Wp + (size_t)srowB * D_MODEL + kn_ + skg, &Bs[buf_][sbB0]);                   \
    dma16(Wp + (size_t)(srowB + 16) * D_MODEL + kn_ + skg, &Bs[buf_][sbB1]);            \
  }

  floatx4 acc[I][4];
#pragma unroll
  for (int i = 0; i < I; i++)
#pragma unroll
    for (int j = 0; j < 4; j++) acc[i][j] = (floatx4){0.f, 0.f, 0.f, 0.f};

  STAGE_G(0, 0);
  STAGE_G(1, 1);

  int cb = 0;
  for (int kt = 0; kt < NKT; kt++) {
    if (kt < NKT - 1) {
      if constexpr (MODE == 0) WAIT_VM(4);
      else                     WAIT_VM(3);
    } else {
      WAIT_VM(0);
    }
    BARRIER();
    if (kt + 2 < NKT) {
      const int nb = (cb == 0) ? 2 : cb - 1;
      STAGE_G(kt + 2, nb);
    }
    const __hip_bfloat16* Ac = As[cb];
    const __hip_bfloat16* Bc = Bs[cb];
    short8 af[I], bfr[4];
#pragma unroll
    for (int i = 0; i < I; i++) af[i] = *(const short8*)&Ac[(wm + i * 16 + lr) * 32 + lq * 8];
#pragma unroll
    for (int j = 0; j < 4; j++) bfr[j] = *(const short8*)&Bc[(wn + j * 16 + lr) * 32 + lq * 8];
#pragma unroll
    for (int i = 0; i < I; i++)
#pragma unroll
      for (int j = 0; j < 4; j++) acc[i][j] = mfma_bf16(af[i], bfr[j], acc[i][j]);
    cb = (cb == 2) ? 0 : cb + 1;
  }
#undef STAGE_G

#pragma unroll
  for (int j = 0; j < 4; j++) {
    const int n = n0 + wn + j * 16 + lr;
    const float bv = bias[n];
#pragma unroll
    for (int i = 0; i < I; i++) {
      const int mb = m0 + wm + i * 16 + lq * 4;
      if (MODE == 0) {
        __hip_bfloat16* O = (__hip_bfloat16*)outp;
        const int b = mb >> 11, s = mb & 2047;
        const int h = n >> 6, d = n & 63;
        if (z == 2) {
          ushort4 pk;
          __hip_bfloat16* pp = (__hip_bfloat16*)&pk;
#pragma unroll
          for (int r = 0; r < 4; r++) pp[r] = __float2bfloat16(acc[i][j][r] + bv);
          *(ushort4*)(O + (((size_t)(b * NH + h) * HD + d) * SEQ + s)) = pk;
        } else {
#pragma unroll
          for (int r = 0; r < 4; r++)
            O[(((size_t)(b * NH + h) * SEQ + (s + r)) * HD) + d] =
                __float2bfloat16((acc[i][j][r] + bv) * scale);
        }
      } else {
#pragma unroll
        for (int r = 0; r < 4; r++)
          ((float*)outp)[(size_t)(mb + r) * D_MODEL + n] = acc[i][j][r] + bv;
      }
    }
  }
}

// ---------------- flash attention, causal, no-max softmax ----------------
// Grid (32 bh, 16 p), 256 thr (4 waves = 2 wr x 2 wb). XCD: linear%8 = bh%8.
// Wave: 32 queries (2 rt frags of 16) x 64-key window (wb half of a 128-key tile).
// Block: Q-tiles p and 31-p (64 rows each) -> uniform 17 tile-iterations.
// S^T orientation (one query per lane); P -> PV B-frag via ds_bpermute.
// K/V fragments read once per wave-iter, shared across both rt (halves LDS/pair).
__global__ __launch_bounds__(256, 2) void attn_kernel(
    const __hip_bfloat16* __restrict__ Q, const __hip_bfloat16* __restrict__ Kg,
    const __hip_bfloat16* __restrict__ Vt, __hip_bfloat16* __restrict__ ctx) {
  const int bh = blockIdx.x;
  const int b = bh >> 4, h = bh & 15;
  const int p = blockIdx.y;  // 0..15
  const int t = threadIdx.x, lane = t & 63, w = t >> 6;
  const int lr = lane & 15, lq = lane >> 4;
  const int wr = w & 1, wb = w >> 1;

  __shared__ __attribute__((aligned(16))) __hip_bfloat16 Ks[2][128 * 64];   // [key][d] swz3
  __shared__ __attribute__((aligned(16))) __hip_bfloat16 VTs[2][64 * 128];  // [d][key] swz4
  __shared__ __attribute__((aligned(16))) float dumpO[2048];                // 8 KB
  __shared__ float dumpL[256];

  const __hip_bfloat16* Qb = Q + (size_t)bh * SEQ * HD;
  const __hip_bfloat16* Kb = Kg + (size_t)bh * SEQ * HD;
  const __hip_bfloat16* Vb = Vt + (size_t)bh * HD * SEQ;

  // Q fragments, both phases, loaded before any DMA (clean vmcnt accounting)
  short8 qf[2][2][2];  // [ph][rt][ks]
#pragma unroll
  for (int ph = 0; ph < 2; ph++) {
    const int qt = ph ? 31 - p : p;
#pragma unroll
    for (int rt = 0; rt < 2; rt++)
#pragma unroll
      for (int ks = 0; ks < 2; ks++)
        qf[ph][rt][ks] = *(const short8*)(Qb + (size_t)(qt * 64 + wr * 32 + rt * 16 + lr) * HD +
                                          ks * 32 + lq * 8);
  }

  // ---- staging lane constants ----
  // K tile: 128 rows x 64 d (128 B/row), 8 granules of 16 B, swz3. 4 insts/wave (8 rows each).
  const int krow = (w << 5) + (lane >> 3);      // + i*8
  const int ksl = lane & 7;
  // V tile: 64 rows (d) x 128 keys (256 B/row), 16 granules, swz4. 4 insts/wave (4 rows each).
  const int vrow = (w << 4) + (lane >> 4);      // + i*4
  const int vsl = lane & 15;

#define STAGE(tb, nb)                                                                     \
  {                                                                                       \
    _Pragma("unroll") for (int i = 0; i < 4; i++) {                                       \
      const int r_ = krow + i * 8;                                                        \
      dma16(Kb + ((size_t)((tb) + r_) << 6) + ((ksl ^ (r_ & 7)) << 3),                    \
            &Ks[nb][((w << 5) + i * 8) << 6]);                                            \
    }                                                                                     \
    _Pragma("unroll") for (int i = 0; i < 4; i++) {                                       \
      const int r_ = vrow + i * 4;                                                        \
      dma16(Vb + (size_t)r_ * SEQ + (tb) + ((vsl ^ (r_ & 15)) << 3),                      \
            &VTs[nb][((w << 4) + i * 4) << 7]);                                           \
    }                                                                                     \
  }

  const int nktA = (p + 2) >> 1;
  const int TOT = 17;
#define KTN(gs) (((gs) < nktA) ? (gs) : (gs)-nktA)

  STAGE(0, 0);
  int g = 0;

  const int idx0 = (lr + ((lq & 1) << 5)) << 2;  // bpermute byte index
  const int idx1 = idx0 + 64;
  const bool hi = (lq >= 2);

  // lane-invariant parts of LDS read addresses (element offsets)
  const int kfb0 = (lr << 6) + ((lq ^ (lr & 7)) << 3);          // ks=0
  const int kfb1 = (lr << 6) + (((4 + lq) ^ (lr & 7)) << 3);    // ks=1
  const int vfb0 = (lr << 7) + ((((wb << 3) + lq) ^ lr) << 3);        // ks=0
  const int vfb1 = (lr << 7) + ((((wb << 3) + 4 + lq) ^ lr) << 3);    // ks=1
  const int kwoff = wb << 12;  // wb*64 rows * 64 elems

  for (int ph = 0; ph < 2; ph++) {
    const int qt = ph ? 31 - p : p;
    const int nkt = (qt + 2) >> 1;
    const int qbase = qt * 64 + wr * 32;
    const int qmaxw = qbase + 31;

    floatx4 o[2][4];
#pragma unroll
    for (int rt = 0; rt < 2; rt++)
#pragma unroll
      for (int dt = 0; dt < 4; dt++) o[rt][dt] = (floatx4){0.f, 0.f, 0.f, 0.f};
    float ls[2] = {0.f, 0.f};

    for (int kt = 0; kt < nkt; kt++, g++) {
      WAIT_VM(0);
      BARRIER();
      if (g + 1 < TOT) STAGE(KTN(g + 1) << 7, (g + 1) & 1);

      const int n0w = (kt << 7) + (wb << 6);
      if (n0w <= qmaxw) {
        const int cbuf = g & 1;
        const __hip_bfloat16* Kc = &Ks[cbuf][kwoff];
        const __hip_bfloat16* Vc = VTs[cbuf];

        // load K frags once (shared by both rt)
        short8 kf[2][4];
#pragma unroll
        for (int nt = 0; nt < 4; nt++) {
          kf[0][nt] = *(const short8*)&Kc[(nt << 10) + kfb0];
          kf[1][nt] = *(const short8*)&Kc[(nt << 10) + kfb1];
        }
        // S^T = K Q^T
        floatx4 s[2][4];
#pragma unroll
        for (int rt = 0; rt < 2; rt++)
#pragma unroll
          for (int nt = 0; nt < 4; nt++) s[rt][nt] = (floatx4){0.f, 0.f, 0.f, 0.f};
#pragma unroll
        for (int ks = 0; ks < 2; ks++)
#pragma unroll
          for (int nt = 0; nt < 4; nt++) {
            s[0][nt] = mfma_bf16(kf[ks][nt], qf[ph][0][ks], s[0][nt]);
            s[1][nt] = mfma_bf16(kf[ks][nt], qf[ph][1][ks], s[1][nt]);
          }

        // softmax numerators: raw v_exp, round-half-up bf16 pair pack
        int pkA[2][4], pkB[2][4];
        const bool need_mask = (n0w + 63 > qbase);
#pragma unroll
        for (int rt = 0; rt < 2; rt++) {
          const int q = qbase + rt * 16 + lr;
#pragma unroll
          for (int nt = 0; nt < 4; nt++) {
            const int kbase = n0w + (nt << 4) + (lq << 2);
            float x0 = s[rt][nt][0], x1 = s[rt][nt][1], x2 = s[rt][nt][2], x3 = s[rt][nt][3];
            if (need_mask) {
              x0 = (kbase + 0 <= q) ? x0 : -1e30f;
              x1 = (kbase + 1 <= q) ? x1 : -1e30f;
              x2 = (kbase + 2 <= q) ? x2 : -1e30f;
              x3 = (kbase + 3 <= q) ? x3 : -1e30f;
            }
            const float p0 = __builtin_amdgcn_exp2f(x0);
            const float p1 = __builtin_amdgcn_exp2f(x1);
            const float p2 = __builtin_amdgcn_exp2f(x2);
            const float p3 = __builtin_amdgcn_exp2f(x3);
            ls[rt] += (p0 + p1) + (p2 + p3);
            pkA[rt][nt] = pack2bf(p0, p1);
            pkB[rt][nt] = pack2bf(p2, p3);
          }
        }

        // P^T B-frags via bpermute; O^T += V^T P^T
#pragma unroll
        for (int ks = 0; ks < 2; ks++) {
          short8 pf[2];
#pragma unroll
          for (int rt = 0; rt < 2; rt++) {
            const int t0 = 2 * ks, t1 = 2 * ks + 1;
            int c0a = __builtin_amdgcn_ds_bpermute(idx0, pkA[rt][t0]);
            int c0b = __builtin_amdgcn_ds_bpermute(idx0, pkA[rt][t1]);
            int c1a = __builtin_amdgcn_ds_bpermute(idx0, pkB[rt][t0]);
            int c1b = __builtin_amdgcn_ds_bpermute(idx0, pkB[rt][t1]);
            int c2a = __builtin_amdgcn_ds_bpermute(idx1, pkA[rt][t0]);
            int c2b = __builtin_amdgcn_ds_bpermute(idx1, pkA[rt][t1]);
            int c3a = __builtin_amdgcn_ds_bpermute(idx1, pkB[rt][t0]);
            int c3b = __builtin_amdgcn_ds_bpermute(idx1, pkB[rt][t1]);
            intx4 bi;
            bi[0] = hi ? c0b : c0a;
            bi[1] = hi ? c1b : c1a;
            bi[2] = hi ? c2b : c2a;
            bi[3] = hi ? c3b : c3a;
            pf[rt] = __builtin_bit_cast(short8, bi);
          }
          const int vfb = ks ? vfb1 : vfb0;
#pragma unroll
          for (int dt = 0; dt < 4; dt++) {
            short8 vf = *(const short8*)&Vc[(dt << 11) + vfb];
            o[0][dt] = mfma_bf16(vf, pf[0], o[0][dt]);
            o[1][dt] = mfma_bf16(vf, pf[1], o[1][dt]);
          }
        }
      }
    }

    // ---- phase epilogue: merge wb partials via LDS, normalize, store ----
    const int dbase = (wr << 10) + (lane << 4);
    BARRIER();
    if (wb == 1) {
#pragma unroll
      for (int dt = 0; dt < 4; dt++) *(floatx4*)&dumpO[dbase + (dt << 2)] = o[0][dt];
      dumpL[(wr << 7) + (lane << 1)] = ls[0];
      dumpL[(wr << 7) + (lane << 1) + 1] = ls[1];
      WAIT_LGKM();
    }
    BARRIER();
    if (wb == 0) {
#pragma unroll
      for (int dt = 0; dt < 4; dt++) o[0][dt] += *(const floatx4*)&dumpO[dbase + (dt << 2)];
      ls[0] += dumpL[(wr << 7) + (lane << 1)];
      ls[1] += dumpL[(wr << 7) + (lane << 1) + 1];
    }
    BARRIER();
    if (wb == 1) {
#pragma unroll
      for (int dt = 0; dt < 4; dt++) *(floatx4*)&dumpO[dbase + (dt << 2)] = o[1][dt];
      WAIT_LGKM();
    }
    BARRIER();
    if (wb == 0) {
#pragma unroll
      for (int dt = 0; dt < 4; dt++) o[1][dt] += *(const floatx4*)&dumpO[dbase + (dt << 2)];
      float inv[2];
#pragma unroll
      for (int rt = 0; rt < 2; rt++) {
        float v = ls[rt];
        v += __shfl_xor(v, 16);
        v += __shfl_xor(v, 32);
        inv[rt] = 1.f / v;
      }
#pragma unroll
      for (int rt = 0; rt < 2; rt++) {
        const int row = qbase + rt * 16 + lr;
        __hip_bfloat16* cp = ctx + (size_t)b * SEQ * D_MODEL + (size_t)row * D_MODEL + h * HD;
#pragma unroll
        for (int dt = 0; dt < 4; dt++) {
          ushort4 pk;
          __hip_bfloat16* pp = (__hip_bfloat16*)&pk;
#pragma unroll
          for (int r = 0; r < 4; r++) pp[r] = __float2bfloat16(o[rt][dt][r] * inv[rt]);
          *(ushort4*)(cp + (dt << 4) + (lq << 2)) = pk;
        }
      }
    }
    // next phase's loop-top BARRIER protects dump buffers
  }
#undef STAGE
#undef KTN
}

extern "C" void kernel_launch(void* const* d_in, const int* in_sizes, int n_in,
                              void* d_out, int out_size, void* d_ws, size_t ws_size,
                              hipStream_t stream) {
  const float* x  = (const float*)d_in[0];
  const float* Wq = (const float*)d_in[1];
  const float* bq = (const float*)d_in[2];
  const float* Wk = (const float*)d_in[3];
  const float* bk = (const float*)d_in[4];
  const float* Wv = (const float*)d_in[5];
  const float* bv = (const float*)d_in[6];
  const float* Wo = (const float*)d_in[7];
  const float* bo = (const float*)d_in[8];

  char* ws = (char*)d_ws;
  const size_t MB = 1u << 20;
  __hip_bfloat16* xb  = (__hip_bfloat16*)(ws + 0 * MB);   // 8 MB; reused as ctx after QKV GEMM
  __hip_bfloat16* wtq = (__hip_bfloat16*)(ws + 8 * MB);
  __hip_bfloat16* wtk = (__hip_bfloat16*)(ws + 10 * MB);
  __hip_bfloat16* wtv = (__hip_bfloat16*)(ws + 12 * MB);
  __hip_bfloat16* wto = (__hip_bfloat16*)(ws + 14 * MB);
  __hip_bfloat16* qb  = (__hip_bfloat16*)(ws + 16 * MB);
  __hip_bfloat16* kb  = (__hip_bfloat16*)(ws + 24 * MB);
  __hip_bfloat16* vt  = (__hip_bfloat16*)(ws + 32 * MB);
  __hip_bfloat16* ctx = xb;  // alias: x no longer needed after QKV projection

  prep_kernel<<<dim3(32, 32, 5), dim3(32, 8), 0, stream>>>(x, xb, Wq, Wk, Wv, Wo,
                                                           wtq, wtk, wtv, wto);
  gemm_kernel<0><<<dim3(8, 3, 32), 256, 0, stream>>>(xb, wtq, wtk, wtv, bq, bk, bv,
                                                     (void*)qb, (void*)kb, (void*)vt);
  attn_kernel<<<dim3(32, 16), 256, 0, stream>>>(qb, kb, vt, ctx);
  gemm_kernel<1><<<dim3(8, 1, 64), 256, 0, stream>>>(ctx, wto, wto, wto, bo, bo, bo,
                                                     d_out, d_out, d_out);
}

// Round 7
// 192.335 us; speedup vs baseline: 1.0390x; 1.0118x over previous
//
#include <hip/hip_runtime.h>
#include <hip/hip_bf16.h>

typedef __attribute__((ext_vector_type(8))) short short8;
typedef __attribute__((ext_vector_type(4))) float floatx4;
typedef __attribute__((ext_vector_type(4))) int intx4;

#define D_MODEL 1024
#define SEQ     2048
#define NB      2
#define NH      16
#define HD      64
#define MROWS   4096   // NB*SEQ
#define CZ      (0.125f * 1.44269504f)   // 1/sqrt(64) * log2(e)

__device__ __forceinline__ floatx4 mfma_bf16(short8 a, short8 b, floatx4 c) {
  return __builtin_amdgcn_mfma_f32_16x16x32_bf16(a, b, c, 0, 0, 0);
}

// async global -> LDS, 16 B per lane. LDS dest = wave-uniform base + lane*16.
__device__ __forceinline__ void dma16(const __hip_bfloat16* g, __hip_bfloat16* l) {
  __builtin_amdgcn_global_load_lds(
      (const __attribute__((address_space(1))) void*)g,
      (__attribute__((address_space(3))) void*)l, 16, 0, 0);
}
#define WAIT_VM(n)  __asm__ __volatile__("s_waitcnt vmcnt(" #n ")" ::: "memory")
#define BARRIER()   __asm__ __volatile__("s_barrier" ::: "memory")
#define WAIT_LGKM() __asm__ __volatile__("s_waitcnt lgkmcnt(0)" ::: "memory")

// round-half-up bf16 pair pack
__device__ __forceinline__ int pack2bf(float a, float b) {
  unsigned ua = __builtin_bit_cast(unsigned, a) + 0x8000u;
  unsigned ub = __builtin_bit_cast(unsigned, b) + 0x8000u;
  return (int)__builtin_amdgcn_perm(ub, ua, 0x07060302u);
}

// ---------------- prep: W transpose (z<4) + x fp32->bf16 (z==4) ----------------
__global__ void prep_kernel(const float* __restrict__ x, __hip_bfloat16* __restrict__ xb,
                            const float* __restrict__ W0, const float* __restrict__ W1,
                            const float* __restrict__ W2, const float* __restrict__ W3,
                            __hip_bfloat16* __restrict__ T0, __hip_bfloat16* __restrict__ T1,
                            __hip_bfloat16* __restrict__ T2, __hip_bfloat16* __restrict__ T3) {
  const int z = blockIdx.z;
  if (z == 4) {
    const int tid = threadIdx.y * 32 + threadIdx.x;
    const int base = ((blockIdx.y * 32 + blockIdx.x) * 256 + tid) * 16;
#pragma unroll
    for (int c = 0; c < 4; c++) {
      float4 v = *(const float4*)(x + base + c * 4);
      __hip_bfloat16 tmp[4];
      tmp[0] = __float2bfloat16(v.x);
      tmp[1] = __float2bfloat16(v.y);
      tmp[2] = __float2bfloat16(v.z);
      tmp[3] = __float2bfloat16(v.w);
      *(ushort4*)(xb + base + c * 4) = *(ushort4*)tmp;
    }
    return;
  }
  const float* W = (z == 0) ? W0 : (z == 1) ? W1 : (z == 2) ? W2 : W3;
  __hip_bfloat16* Wt = (z == 0) ? T0 : (z == 1) ? T1 : (z == 2) ? T2 : T3;
  __shared__ float tile[32][33];
  int k0 = blockIdx.x * 32, n0 = blockIdx.y * 32;
  int tx = threadIdx.x, ty = threadIdx.y;  // block (32,8)
#pragma unroll
  for (int i = 0; i < 4; i++)
    tile[ty + 8 * i][tx] = W[(size_t)(k0 + ty + 8 * i) * D_MODEL + n0 + tx];
  __syncthreads();
#pragma unroll
  for (int i = 0; i < 4; i++)
    Wt[(size_t)(n0 + ty + 8 * i) * D_MODEL + k0 + tx] = __float2bfloat16(tile[tx][ty + 8 * i]);
}

// ---------------- GEMM: Y = (X @ W + b) * scale ----------------
// Triple-buffered LDS, raw s_barrier + fine-grained vmcnt (never 0 mid-loop).
// MODE 0: MT=128; grid (8 n, 3 z, 32 m). z=0 -> Q bf16 [bh][s][d] * CZ;
//         z=1 -> K bf16 [bh][s][d]; z=2 -> V^T bf16 [bh][d][s].
// MODE 1: MT=64; grid (8 n, 1, 64 m). fp32 row-major out.
template <int MODE>
__global__ __launch_bounds__(256) void gemm_kernel(
    const __hip_bfloat16* __restrict__ X,
    const __hip_bfloat16* __restrict__ Wt0, const __hip_bfloat16* __restrict__ Wt1,
    const __hip_bfloat16* __restrict__ Wt2,
    const float* __restrict__ b0, const float* __restrict__ b1, const float* __restrict__ b2,
    void* __restrict__ out0, void* __restrict__ out1, void* __restrict__ out2) {
  constexpr int MT = (MODE == 0) ? 128 : 64;
  constexpr int I = MT / 32;
  constexpr int NKT = D_MODEL / 32;

  const int z = blockIdx.y;
  const __hip_bfloat16* Wt = (z == 0) ? Wt0 : (z == 1) ? Wt1 : Wt2;
  const float* bias = (z == 0) ? b0 : (z == 1) ? b1 : b2;
  void* outp = (z == 0) ? out0 : (z == 1) ? out1 : out2;
  const float scale = (MODE == 0 && z == 0) ? CZ : 1.f;

  __shared__ __attribute__((aligned(16))) __hip_bfloat16 As[3][MT * 32];
  __shared__ __attribute__((aligned(16))) __hip_bfloat16 Bs[3][128 * 32];

  const int n0 = blockIdx.x * 128;
  const int m0 = blockIdx.z * MT;
  const int t = threadIdx.x;
  const int lane = t & 63, w = t >> 6;
  const int wm = (w >> 1) * (MT / 2), wn = (w & 1) * 64;
  const int lr = lane & 15;
  const int lq = lane >> 4;

  const __hip_bfloat16* Xp = X + (size_t)m0 * D_MODEL;
  const __hip_bfloat16* Wp = Wt + (size_t)n0 * D_MODEL;

  const int lrow = lane >> 2;
  const int skg = (lane & 3) << 3;
  const int srowA = ((MT == 128) ? (w << 5) : (w << 4)) + lrow;
  const int sbA0 = (((MT == 128) ? (w << 5) : (w << 4)) << 5);
  const int sbA1 = sbA0 + (16 << 5);
  const int srowB = (w << 5) + lrow;
  const int sbB0 = ((w << 5) << 5);
  const int sbB1 = sbB0 + (16 << 5);

#define STAGE_G(kt_, buf_)                                                              \
  {                                                                                     \
    const int kn_ = (kt_) * 32;                                                         \
    dma16(Xp + (size_t)srowA * D_MODEL + kn_ + skg, &As[buf_][sbA0]);                   \
    if (MT == 128) dma16(Xp + (size_t)(srowA + 16) * D_MODEL + kn_ + skg, &As[buf_][sbA1]); \
    dma16(Wp + (size_t)srowB * D_MODEL + kn_ + skg, &Bs[buf_][sbB0]);                   \
    dma16(Wp + (size_t)(srowB + 16) * D_MODEL + kn_ + skg, &Bs[buf_][sbB1]);            \
  }

  floatx4 acc[I][4];
#pragma unroll
  for (int i = 0; i < I; i++)
#pragma unroll
    for (int j = 0; j < 4; j++) acc[i][j] = (floatx4){0.f, 0.f, 0.f, 0.f};

  STAGE_G(0, 0);
  STAGE_G(1, 1);

  int cb = 0;
  for (int kt = 0; kt < NKT; kt++) {
    if (kt < NKT - 1) {
      if constexpr (MODE == 0) WAIT_VM(4);
      else                     WAIT_VM(3);
    } else {
      WAIT_VM(0);
    }
    BARRIER();
    if (kt + 2 < NKT) {
      const int nb = (cb == 0) ? 2 : cb - 1;
      STAGE_G(kt + 2, nb);
    }
    const __hip_bfloat16* Ac = As[cb];
    const __hip_bfloat16* Bc = Bs[cb];
    short8 af[I], bfr[4];
#pragma unroll
    for (int i = 0; i < I; i++) af[i] = *(const short8*)&Ac[(wm + i * 16 + lr) * 32 + lq * 8];
#pragma unroll
    for (int j = 0; j < 4; j++) bfr[j] = *(const short8*)&Bc[(wn + j * 16 + lr) * 32 + lq * 8];
#pragma unroll
    for (int i = 0; i < I; i++)
#pragma unroll
      for (int j = 0; j < 4; j++) acc[i][j] = mfma_bf16(af[i], bfr[j], acc[i][j]);
    cb = (cb == 2) ? 0 : cb + 1;
  }
#undef STAGE_G

#pragma unroll
  for (int j = 0; j < 4; j++) {
    const int n = n0 + wn + j * 16 + lr;
    const float bv = bias[n];
#pragma unroll
    for (int i = 0; i < I; i++) {
      const int mb = m0 + wm + i * 16 + lq * 4;
      if (MODE == 0) {
        __hip_bfloat16* O = (__hip_bfloat16*)outp;
        const int b = mb >> 11, s = mb & 2047;
        const int h = n >> 6, d = n & 63;
        if (z == 2) {
          ushort4 pk;
          __hip_bfloat16* pp = (__hip_bfloat16*)&pk;
#pragma unroll
          for (int r = 0; r < 4; r++) pp[r] = __float2bfloat16(acc[i][j][r] + bv);
          *(ushort4*)(O + (((size_t)(b * NH + h) * HD + d) * SEQ + s)) = pk;
        } else {
#pragma unroll
          for (int r = 0; r < 4; r++)
            O[(((size_t)(b * NH + h) * SEQ + (s + r)) * HD) + d] =
                __float2bfloat16((acc[i][j][r] + bv) * scale);
        }
      } else {
#pragma unroll
        for (int r = 0; r < 4; r++)
          ((float*)outp)[(size_t)(mb + r) * D_MODEL + n] = acc[i][j][r] + bv;
      }
    }
  }
}

// ---------------- flash attention, causal, no-max softmax, occupancy-first ----------------
// Grid (32 bh, 32 qt), qt = 31-blockIdx.y (largest first -> backfill balances triangular work).
// Block 256 thr = 4 waves: wr = w&1 (32-q half of 64-row tile), wb = w>>1 (interleaved
// 16-key groups of a 64-key tile). LDS 32 KB -> 4 blocks/CU (4 waves/SIMD).
// S^T orientation; P -> PV B-frag via ds_bpermute; double-buffered DMA staging.
__global__ __launch_bounds__(256, 4) void attn_kernel(
    const __hip_bfloat16* __restrict__ Q, const __hip_bfloat16* __restrict__ Kg,
    const __hip_bfloat16* __restrict__ Vt, __hip_bfloat16* __restrict__ ctx) {
  const int bh = blockIdx.x;
  const int b = bh >> 4, h = bh & 15;
  const int qt = 31 - blockIdx.y;
  const int t = threadIdx.x, lane = t & 63, w = t >> 6;
  const int lr = lane & 15, lq = lane >> 4;
  const int wr = w & 1, wb = w >> 1;

  __shared__ __attribute__((aligned(16))) __hip_bfloat16 Ks[2][64 * 64];   // 8 KB each
  __shared__ __attribute__((aligned(16))) __hip_bfloat16 VTs[2][64 * 64];  // 8 KB each

  const __hip_bfloat16* Qb = Q + (size_t)bh * SEQ * HD;
  const __hip_bfloat16* Kb = Kg + (size_t)bh * SEQ * HD;
  const __hip_bfloat16* Vb = Vt + (size_t)bh * HD * SEQ;

  const int qrow0 = qt * 64 + wr * 32;  // this wave's first query row

  // Q fragments (before any DMA -> clean vmcnt accounting)
  short8 qf[2][2];  // [rt][ks]
#pragma unroll
  for (int rt = 0; rt < 2; rt++)
#pragma unroll
    for (int ks = 0; ks < 2; ks++)
      qf[rt][ks] = *(const short8*)(Qb + (size_t)(qrow0 + rt * 16 + lr) * HD + ks * 32 + lq * 8);

  // staging constants: both tiles are 64 rows x 64 elems (128 B row, 8 granules, swz3)
  const int srow = (w << 4) + (lane >> 3);  // rows srow, srow+8
  const int sgl = lane & 7;
  const int sb0 = (w << 4) << 6;
  const int sb1 = ((w << 4) + 8) << 6;

#define STAGE(tb, nb)                                                                  \
  {                                                                                    \
    const int r0 = srow, r1 = srow + 8;                                                \
    dma16(Kb + ((size_t)((tb) + r0) << 6) + ((sgl ^ (r0 & 7)) << 3), &Ks[nb][sb0]);    \
    dma16(Kb + ((size_t)((tb) + r1) << 6) + ((sgl ^ (r1 & 7)) << 3), &Ks[nb][sb1]);    \
    dma16(Vb + (size_t)r0 * SEQ + (tb) + ((sgl ^ (r0 & 7)) << 3), &VTs[nb][sb0]);      \
    dma16(Vb + (size_t)r1 * SEQ + (tb) + ((sgl ^ (r1 & 7)) << 3), &VTs[nb][sb1]);      \
  }

  const int nkt = qt + 1;
  STAGE(0, 0);

  floatx4 o[2][4];
#pragma unroll
  for (int rt = 0; rt < 2; rt++)
#pragma unroll
    for (int dt = 0; dt < 4; dt++) o[rt][dt] = (floatx4){0.f, 0.f, 0.f, 0.f};
  float ls[2] = {0.f, 0.f};

  const int idx0 = (lr + ((lq & 1) << 5)) << 2;  // bpermute byte indices
  const int idx1 = idx0 + 64;
  const bool hi = (lq >= 2);

  // LDS read offsets (element units)
  const int kfb0 = ((wb << 4) + lr) << 6;                  // + nt*2048
  const int kg0 = ((lq ^ (lr & 7)) << 3);                  // ks=0 granule
  const int kg1 = (((4 + lq) ^ (lr & 7)) << 3);            // ks=1
  const int vg = ((((lq & 2) << 1) + (wb << 1) + (lq & 1)) ^ (lr & 7)) << 3;

  for (int kt = 0; kt < nkt; kt++) {
    WAIT_VM(0);
    BARRIER();
    if (kt + 1 < nkt) STAGE((kt + 1) << 6, (kt + 1) & 1);

    const int kw0 = (kt << 6) + (wb << 4);  // wave's first key
    if (kw0 <= qrow0 + 31) {
      const __hip_bfloat16* Kc = Ks[kt & 1];
      const __hip_bfloat16* Vc = VTs[kt & 1];

      // K frags (shared across rt): row = nt*32 + wb*16 + lr
      short8 kf[2][2];  // [ks][nt]
#pragma unroll
      for (int nt = 0; nt < 2; nt++) {
        kf[0][nt] = *(const short8*)&Kc[(nt << 11) + kfb0 + kg0];
        kf[1][nt] = *(const short8*)&Kc[(nt << 11) + kfb0 + kg1];
      }
      // S^T = K Q^T
      floatx4 s[2][2];  // [rt][nt]
#pragma unroll
      for (int rt = 0; rt < 2; rt++)
#pragma unroll
        for (int nt = 0; nt < 2; nt++) s[rt][nt] = (floatx4){0.f, 0.f, 0.f, 0.f};
#pragma unroll
      for (int ks = 0; ks < 2; ks++)
#pragma unroll
        for (int nt = 0; nt < 2; nt++) {
          s[0][nt] = mfma_bf16(kf[ks][nt], qf[0][ks], s[0][nt]);
          s[1][nt] = mfma_bf16(kf[ks][nt], qf[1][ks], s[1][nt]);
        }

      // numerators (mask only near the diagonal), pack to bf16 pairs
      const bool need_mask = (kw0 + 47 > qrow0);
      int pkA[2][2], pkB[2][2];  // [rt][nt]
#pragma unroll
      for (int rt = 0; rt < 2; rt++) {
        const int q = qrow0 + rt * 16 + lr;
#pragma unroll
        for (int nt = 0; nt < 2; nt++) {
          const int kbase = (kt << 6) + (nt << 5) + (wb << 4) + (lq << 2);
          float x0 = s[rt][nt][0], x1 = s[rt][nt][1], x2 = s[rt][nt][2], x3 = s[rt][nt][3];
          if (need_mask) {
            x0 = (kbase + 0 <= q) ? x0 : -1e30f;
            x1 = (kbase + 1 <= q) ? x1 : -1e30f;
            x2 = (kbase + 2 <= q) ? x2 : -1e30f;
            x3 = (kbase + 3 <= q) ? x3 : -1e30f;
          }
          const float p0 = __builtin_amdgcn_exp2f(x0);
          const float p1 = __builtin_amdgcn_exp2f(x1);
          const float p2 = __builtin_amdgcn_exp2f(x2);
          const float p3 = __builtin_amdgcn_exp2f(x3);
          ls[rt] += (p0 + p1) + (p2 + p3);
          pkA[rt][nt] = pack2bf(p0, p1);
          pkB[rt][nt] = pack2bf(p2, p3);
        }
      }

      // P^T B-frags via bpermute; O^T += V^T P^T (single 32-key ks-step)
      short8 pf[2];
#pragma unroll
      for (int rt = 0; rt < 2; rt++) {
        int c0a = __builtin_amdgcn_ds_bpermute(idx0, pkA[rt][0]);
        int c0b = __builtin_amdgcn_ds_bpermute(idx0, pkA[rt][1]);
        int c1a = __builtin_amdgcn_ds_bpermute(idx0, pkB[rt][0]);
        int c1b = __builtin_amdgcn_ds_bpermute(idx0, pkB[rt][1]);
        int c2a = __builtin_amdgcn_ds_bpermute(idx1, pkA[rt][0]);
        int c2b = __builtin_amdgcn_ds_bpermute(idx1, pkA[rt][1]);
        int c3a = __builtin_amdgcn_ds_bpermute(idx1, pkB[rt][0]);
        int c3b = __builtin_amdgcn_ds_bpermute(idx1, pkB[rt][1]);
        intx4 bi;
        bi[0] = hi ? c0b : c0a;
        bi[1] = hi ? c1b : c1a;
        bi[2] = hi ? c2b : c2a;
        bi[3] = hi ? c3b : c3a;
        pf[rt] = __builtin_bit_cast(short8, bi);
      }
#pragma unroll
      for (int dt = 0; dt < 4; dt++) {
        short8 vf = *(const short8*)&Vc[(((dt << 4) + lr) << 6) + vg];
        o[0][dt] = mfma_bf16(vf, pf[0], o[0][dt]);
        o[1][dt] = mfma_bf16(vf, pf[1], o[1][dt]);
      }
    }
  }

  // ---- epilogue: merge wb partials via (now free) LDS buffers ----
  BARRIER();
  if (wb == 1) {
    float* d0 = (float*)&Ks[0][0];   // rt0 partials (8 KB)
    float* d1 = (float*)&Ks[1][0];   // rt1 partials (8 KB)
    float* dl = (float*)&VTs[0][0];  // l partials
    const int base = (wr << 10) + (lane << 4);
#pragma unroll
    for (int dt = 0; dt < 4; dt++) *(floatx4*)&d0[base + (dt << 2)] = o[0][dt];
#pragma unroll
    for (int dt = 0; dt < 4; dt++) *(floatx4*)&d1[base + (dt << 2)] = o[1][dt];
    dl[(wr << 7) + (lane << 1)] = ls[0];
    dl[(wr << 7) + (lane << 1) + 1] = ls[1];
    WAIT_LGKM();
  }
  BARRIER();
  if (wb == 0) {
    const float* d0 = (const float*)&Ks[0][0];
    const float* d1 = (const float*)&Ks[1][0];
    const float* dl = (const float*)&VTs[0][0];
    const int base = (wr << 10) + (lane << 4);
#pragma unroll
    for (int dt = 0; dt < 4; dt++) {
      o[0][dt] += *(const floatx4*)&d0[base + (dt << 2)];
      o[1][dt] += *(const floatx4*)&d1[base + (dt << 2)];
    }
    ls[0] += dl[(wr << 7) + (lane << 1)];
    ls[1] += dl[(wr << 7) + (lane << 1) + 1];
    float inv[2];
#pragma unroll
    for (int rt = 0; rt < 2; rt++) {
      float v = ls[rt];
      v += __shfl_xor(v, 16);
      v += __shfl_xor(v, 32);
      inv[rt] = 1.f / v;
    }
#pragma unroll
    for (int rt = 0; rt < 2; rt++) {
      const int row = qrow0 + rt * 16 + lr;
      __hip_bfloat16* cp = ctx + (size_t)b * SEQ * D_MODEL + (size_t)row * D_MODEL + h * HD;
#pragma unroll
      for (int dt = 0; dt < 4; dt++) {
        ushort4 pk;
        __hip_bfloat16* pp = (__hip_bfloat16*)&pk;
#pragma unroll
        for (int r = 0; r < 4; r++) pp[r] = __float2bfloat16(o[rt][dt][r] * inv[rt]);
        *(ushort4*)(cp + (dt << 4) + (lq << 2)) = pk;
      }
    }
  }
#undef STAGE
}

extern "C" void kernel_launch(void* const* d_in, const int* in_sizes, int n_in,
                              void* d_out, int out_size, void* d_ws, size_t ws_size,
                              hipStream_t stream) {
  const float* x  = (const float*)d_in[0];
  const float* Wq = (const float*)d_in[1];
  const float* bq = (const float*)d_in[2];
  const float* Wk = (const float*)d_in[3];
  const float* bk = (const float*)d_in[4];
  const float* Wv = (const float*)d_in[5];
  const float* bv = (const float*)d_in[6];
  const float* Wo = (const float*)d_in[7];
  const float* bo = (const float*)d_in[8];

  char* ws = (char*)d_ws;
  const size_t MB = 1u << 20;
  __hip_bfloat16* xb  = (__hip_bfloat16*)(ws + 0 * MB);   // 8 MB; reused as ctx after QKV GEMM
  __hip_bfloat16* wtq = (__hip_bfloat16*)(ws + 8 * MB);
  __hip_bfloat16* wtk = (__hip_bfloat16*)(ws + 10 * MB);
  __hip_bfloat16* wtv = (__hip_bfloat16*)(ws + 12 * MB);
  __hip_bfloat16* wto = (__hip_bfloat16*)(ws + 14 * MB);
  __hip_bfloat16* qb  = (__hip_bfloat16*)(ws + 16 * MB);
  __hip_bfloat16* kb  = (__hip_bfloat16*)(ws + 24 * MB);
  __hip_bfloat16* vt  = (__hip_bfloat16*)(ws + 32 * MB);
  __hip_bfloat16* ctx = xb;  // alias: x no longer needed after QKV projection

  prep_kernel<<<dim3(32, 32, 5), dim3(32, 8), 0, stream>>>(x, xb, Wq, Wk, Wv, Wo,
                                                           wtq, wtk, wtv, wto);
  gemm_kernel<0><<<dim3(8, 3, 32), 256, 0, stream>>>(xb, wtq, wtk, wtv, bq, bk, bv,
                                                     (void*)qb, (void*)kb, (void*)vt);
  attn_kernel<<<dim3(32, 32), 256, 0, stream>>>(qb, kb, vt, ctx);
  gemm_kernel<1><<<dim3(8, 1, 64), 256, 0, stream>>>(ctx, wto, wto, wto, bo, bo, bo,
                                                     d_out, d_out, d_out);
}

// Round 8
// 190.501 us; speedup vs baseline: 1.0490x; 1.0096x over previous
//
#include <hip/hip_runtime.h>
#include <hip/hip_bf16.h>

typedef __attribute__((ext_vector_type(8))) short short8;
typedef __attribute__((ext_vector_type(4))) float floatx4;
typedef __attribute__((ext_vector_type(4))) int intx4;

#define D_MODEL 1024
#define SEQ     2048
#define NB      2
#define NH      16
#define HD      64
#define MROWS   4096   // NB*SEQ
#define CZ      (0.125f * 1.44269504f)   // 1/sqrt(64) * log2(e)

__device__ __forceinline__ floatx4 mfma_bf16(short8 a, short8 b, floatx4 c) {
  return __builtin_amdgcn_mfma_f32_16x16x32_bf16(a, b, c, 0, 0, 0);
}

// async global -> LDS, 16 B per lane. LDS dest = wave-uniform base + lane*16.
__device__ __forceinline__ void dma16(const __hip_bfloat16* g, __hip_bfloat16* l) {
  __builtin_amdgcn_global_load_lds(
      (const __attribute__((address_space(1))) void*)g,
      (__attribute__((address_space(3))) void*)l, 16, 0, 0);
}
#define WAIT_VM(n)  __asm__ __volatile__("s_waitcnt vmcnt(" #n ")" ::: "memory")
#define BARRIER()   __asm__ __volatile__("s_barrier" ::: "memory")
#define WAIT_LGKM() __asm__ __volatile__("s_waitcnt lgkmcnt(0)" ::: "memory")

// round-half-up bf16 pair pack
__device__ __forceinline__ int pack2bf(float a, float b) {
  unsigned ua = __builtin_bit_cast(unsigned, a) + 0x8000u;
  unsigned ub = __builtin_bit_cast(unsigned, b) + 0x8000u;
  return (int)__builtin_amdgcn_perm(ub, ua, 0x07060302u);
}

// ---------------- prep: W transpose (z<4) + x fp32->bf16 (z==4) ----------------
__global__ void prep_kernel(const float* __restrict__ x, __hip_bfloat16* __restrict__ xb,
                            const float* __restrict__ W0, const float* __restrict__ W1,
                            const float* __restrict__ W2, const float* __restrict__ W3,
                            __hip_bfloat16* __restrict__ T0, __hip_bfloat16* __restrict__ T1,
                            __hip_bfloat16* __restrict__ T2, __hip_bfloat16* __restrict__ T3) {
  const int z = blockIdx.z;
  if (z == 4) {
    const int tid = threadIdx.y * 32 + threadIdx.x;
    const int base = ((blockIdx.y * 32 + blockIdx.x) * 256 + tid) * 16;
#pragma unroll
    for (int c = 0; c < 4; c++) {
      float4 v = *(const float4*)(x + base + c * 4);
      __hip_bfloat16 tmp[4];
      tmp[0] = __float2bfloat16(v.x);
      tmp[1] = __float2bfloat16(v.y);
      tmp[2] = __float2bfloat16(v.z);
      tmp[3] = __float2bfloat16(v.w);
      *(ushort4*)(xb + base + c * 4) = *(ushort4*)tmp;
    }
    return;
  }
  const float* W = (z == 0) ? W0 : (z == 1) ? W1 : (z == 2) ? W2 : W3;
  __hip_bfloat16* Wt = (z == 0) ? T0 : (z == 1) ? T1 : (z == 2) ? T2 : T3;
  __shared__ float tile[32][33];
  int k0 = blockIdx.x * 32, n0 = blockIdx.y * 32;
  int tx = threadIdx.x, ty = threadIdx.y;  // block (32,8)
#pragma unroll
  for (int i = 0; i < 4; i++)
    tile[ty + 8 * i][tx] = W[(size_t)(k0 + ty + 8 * i) * D_MODEL + n0 + tx];
  __syncthreads();
#pragma unroll
  for (int i = 0; i < 4; i++)
    Wt[(size_t)(n0 + ty + 8 * i) * D_MODEL + k0 + tx] = __float2bfloat16(tile[tx][ty + 8 * i]);
}

// ---------------- GEMM: Y = (X @ W + b) * scale ----------------
// Triple-buffered LDS staging, raw s_barrier + fine-grained vmcnt; LDS round-trip
// epilogues -> full 16B (bf16) / 128B-run (fp32) stores.
// MODE 0: MT=128; grid (8 n, 3 z, 32 m). z=0 -> Q bf16 [bh][s][d] * CZ;
//         z=1 -> K bf16 [bh][s][d]; z=2 -> V^T bf16 [bh][d][s].
// MODE 1: MT=64; grid (8 n, 1, 64 m). fp32 row-major out.
template <int MODE>
__global__ __launch_bounds__(256) void gemm_kernel(
    const __hip_bfloat16* __restrict__ X,
    const __hip_bfloat16* __restrict__ Wt0, const __hip_bfloat16* __restrict__ Wt1,
    const __hip_bfloat16* __restrict__ Wt2,
    const float* __restrict__ b0, const float* __restrict__ b1, const float* __restrict__ b2,
    void* __restrict__ out0, void* __restrict__ out1, void* __restrict__ out2) {
  constexpr int MT = (MODE == 0) ? 128 : 64;
  constexpr int I = MT / 32;
  constexpr int NKT = D_MODEL / 32;
  constexpr int SMEM_BYTES = 3 * (MT * 32 + 128 * 32) * 2;  // staging; epilogue aliases it

  const int z = blockIdx.y;
  const __hip_bfloat16* Wt = (z == 0) ? Wt0 : (z == 1) ? Wt1 : Wt2;
  const float* bias = (z == 0) ? b0 : (z == 1) ? b1 : b2;
  void* outp = (z == 0) ? out0 : (z == 1) ? out1 : out2;
  const float scale = (MODE == 0 && z == 0) ? CZ : 1.f;

  __shared__ __attribute__((aligned(16))) char smem[SMEM_BYTES];
  __hip_bfloat16* As = (__hip_bfloat16*)smem;                       // 3 bufs of MT*32
  __hip_bfloat16* Bs = (__hip_bfloat16*)smem + 3 * MT * 32;         // 3 bufs of 128*32
  float* Es = (float*)smem;                                         // epilogue scratch

  const int n0 = blockIdx.x * 128;
  const int m0 = blockIdx.z * MT;
  const int t = threadIdx.x;
  const int lane = t & 63, w = t >> 6;
  const int wm = (w >> 1) * (MT / 2), wn = (w & 1) * 64;
  const int lr = lane & 15;
  const int lq = lane >> 4;

  const __hip_bfloat16* Xp = X + (size_t)m0 * D_MODEL;
  const __hip_bfloat16* Wp = Wt + (size_t)n0 * D_MODEL;

  const int lrow = lane >> 2;
  const int skg = (lane & 3) << 3;
  const int srowA = ((MT == 128) ? (w << 5) : (w << 4)) + lrow;
  const int sbA0 = (((MT == 128) ? (w << 5) : (w << 4)) << 5);
  const int sbA1 = sbA0 + (16 << 5);
  const int srowB = (w << 5) + lrow;
  const int sbB0 = ((w << 5) << 5);
  const int sbB1 = sbB0 + (16 << 5);

#define STAGE_G(kt_, buf_)                                                              \
  {                                                                                     \
    const int kn_ = (kt_) * 32;                                                         \
    __hip_bfloat16* A_ = As + (buf_) * (MT * 32);                                       \
    __hip_bfloat16* B_ = Bs + (buf_) * (128 * 32);                                      \
    dma16(Xp + (size_t)srowA * D_MODEL + kn_ + skg, A_ + sbA0);                         \
    if (MT == 128) dma16(Xp + (size_t)(srowA + 16) * D_MODEL + kn_ + skg, A_ + sbA1);   \
    dma16(Wp + (size_t)srowB * D_MODEL + kn_ + skg, B_ + sbB0);                         \
    dma16(Wp + (size_t)(srowB + 16) * D_MODEL + kn_ + skg, B_ + sbB1);                  \
  }

  floatx4 acc[I][4];
#pragma unroll
  for (int i = 0; i < I; i++)
#pragma unroll
    for (int j = 0; j < 4; j++) acc[i][j] = (floatx4){0.f, 0.f, 0.f, 0.f};

  STAGE_G(0, 0);
  STAGE_G(1, 1);

  int cb = 0;
  for (int kt = 0; kt < NKT; kt++) {
    if (kt < NKT - 1) {
      if constexpr (MODE == 0) WAIT_VM(4);
      else                     WAIT_VM(3);
    } else {
      WAIT_VM(0);
    }
    BARRIER();
    if (kt + 2 < NKT) {
      const int nb = (cb == 0) ? 2 : cb - 1;
      STAGE_G(kt + 2, nb);
    }
    const __hip_bfloat16* Ac = As + cb * (MT * 32);
    const __hip_bfloat16* Bc = Bs + cb * (128 * 32);
    short8 af[I], bfr[4];
#pragma unroll
    for (int i = 0; i < I; i++) af[i] = *(const short8*)&Ac[(wm + i * 16 + lr) * 32 + lq * 8];
#pragma unroll
    for (int j = 0; j < 4; j++) bfr[j] = *(const short8*)&Bc[(wn + j * 16 + lr) * 32 + lq * 8];
#pragma unroll
    for (int i = 0; i < I; i++)
#pragma unroll
      for (int j = 0; j < 4; j++) acc[i][j] = mfma_bf16(af[i], bfr[j], acc[i][j]);
    cb = (cb == 2) ? 0 : cb + 1;
  }
#undef STAGE_G

  // ---- epilogue via LDS round-trip (staging buffers are free now) ----
  float bvj[4];
#pragma unroll
  for (int j = 0; j < 4; j++) bvj[j] = bias[n0 + wn + j * 16 + lr];

  if constexpr (MODE == 1) {
    // fp32 row-major out. Scratch [64 m][132].
    BARRIER();
#pragma unroll
    for (int i = 0; i < I; i++) {
      const int rowb = wm + i * 16 + lq * 4;
#pragma unroll
      for (int j = 0; j < 4; j++)
#pragma unroll
        for (int r = 0; r < 4; r++)
          Es[(rowb + r) * 132 + wn + j * 16 + lr] = acc[i][j][r] + bvj[j];
    }
    WAIT_LGKM();
    BARRIER();
    const int L = t >> 2, nseg = (t & 3) * 32;
    float* op = (float*)outp + (size_t)(m0 + L) * D_MODEL + n0 + nseg;
    const float* src = &Es[L * 132 + nseg];
#pragma unroll
    for (int k = 0; k < 8; k++) *(float4*)(op + 4 * k) = *(const float4*)(src + 4 * k);
  } else if (z != 2) {
    // Q/K bf16 [bh][s][d]. Two chunks of i in {2c, 2c+1}; scratch [64 m][132].
    for (int c = 0; c < 2; c++) {
      BARRIER();
#pragma unroll
      for (int i2 = 0; i2 < 2; i2++) {
        const int i = 2 * c + i2;
        const int rowb = (w >> 1) * 32 + i2 * 16 + lq * 4;
#pragma unroll
        for (int j = 0; j < 4; j++)
#pragma unroll
          for (int r = 0; r < 4; r++)
            Es[(rowb + r) * 132 + wn + j * 16 + lr] = (acc[i][j][r] + bvj[j]) * scale;
      }
      WAIT_LGKM();
      BARRIER();
      const int L = t >> 2, nseg = (t & 3) * 32;
      const int m = m0 + ((L >> 5) << 6) + (c << 5) + (L & 31);
      const int bb = m >> 11, s = m & 2047;
      const int nn = n0 + nseg;
      __hip_bfloat16* op = (__hip_bfloat16*)outp +
          (((size_t)(bb * NH + (nn >> 6)) * SEQ + s) * HD + (nn & 63));
      const float* src = &Es[L * 132 + nseg];
#pragma unroll
      for (int k = 0; k < 4; k++) {
        intx4 pk;
        pk[0] = pack2bf(src[8 * k + 0], src[8 * k + 1]);
        pk[1] = pack2bf(src[8 * k + 2], src[8 * k + 3]);
        pk[2] = pack2bf(src[8 * k + 4], src[8 * k + 5]);
        pk[3] = pack2bf(src[8 * k + 6], src[8 * k + 7]);
        *(intx4*)(op + 8 * k) = pk;
      }
    }
  } else {
    // V^T bf16 [bh][d][s]. Two chunks of j in {2c, 2c+1}; scratch [64 n][132 m].
    for (int c = 0; c < 2; c++) {
      BARRIER();
#pragma unroll
      for (int j2 = 0; j2 < 2; j2++) {
        const int j = 2 * c + j2;
        const int nl = ((w & 1) << 5) + (j2 << 4) + lr;
#pragma unroll
        for (int i = 0; i < I; i++) {
          const int moff = (w >> 1) * 64 + i * 16 + lq * 4;
          floatx4 v = acc[i][j];
          v[0] += bvj[j]; v[1] += bvj[j]; v[2] += bvj[j]; v[3] += bvj[j];
          *(floatx4*)&Es[nl * 132 + moff] = v;
        }
      }
      WAIT_LGKM();
      BARRIER();
      const int nl = t >> 2, mseg = (t & 3) * 32;
      const int n = n0 + ((nl >> 5) << 6) + (c << 5) + (nl & 31);
      const int s0 = m0 & 2047, bb = m0 >> 11;
      __hip_bfloat16* op = (__hip_bfloat16*)outp +
          (((size_t)(bb * NH + (n >> 6)) * HD + (n & 63)) * SEQ + s0 + mseg);
      const float* src = &Es[nl * 132 + mseg];
#pragma unroll
      for (int k = 0; k < 4; k++) {
        intx4 pk;
        pk[0] = pack2bf(src[8 * k + 0], src[8 * k + 1]);
        pk[1] = pack2bf(src[8 * k + 2], src[8 * k + 3]);
        pk[2] = pack2bf(src[8 * k + 4], src[8 * k + 5]);
        pk[3] = pack2bf(src[8 * k + 6], src[8 * k + 7]);
        *(intx4*)(op + 8 * k) = pk;
      }
    }
  }
}

// ---------------- flash attention, causal, no-max softmax, occupancy-first ----------------
// Grid (32 bh, 32 qt), qt = 31-blockIdx.y (largest first -> backfill balances triangular work).
// Block 256 thr = 4 waves: wr = w&1 (32-q half of 64-row tile), wb = w>>1 (interleaved
// 16-key groups of a 64-key tile). LDS 32 KB -> 4 blocks/CU (4 waves/SIMD).
// S^T orientation; P -> PV B-frag via ds_bpermute; double-buffered DMA staging.
__global__ __launch_bounds__(256, 4) void attn_kernel(
    const __hip_bfloat16* __restrict__ Q, const __hip_bfloat16* __restrict__ Kg,
    const __hip_bfloat16* __restrict__ Vt, __hip_bfloat16* __restrict__ ctx) {
  const int bh = blockIdx.x;
  const int b = bh >> 4, h = bh & 15;
  const int qt = 31 - blockIdx.y;
  const int t = threadIdx.x, lane = t & 63, w = t >> 6;
  const int lr = lane & 15, lq = lane >> 4;
  const int wr = w & 1, wb = w >> 1;

  __shared__ __attribute__((aligned(16))) __hip_bfloat16 Ks[2][64 * 64];   // 8 KB each
  __shared__ __attribute__((aligned(16))) __hip_bfloat16 VTs[2][64 * 64];  // 8 KB each

  const __hip_bfloat16* Qb = Q + (size_t)bh * SEQ * HD;
  const __hip_bfloat16* Kb = Kg + (size_t)bh * SEQ * HD;
  const __hip_bfloat16* Vb = Vt + (size_t)bh * HD * SEQ;

  const int qrow0 = qt * 64 + wr * 32;  // this wave's first query row

  // Q fragments (before any DMA -> clean vmcnt accounting)
  short8 qf[2][2];  // [rt][ks]
#pragma unroll
  for (int rt = 0; rt < 2; rt++)
#pragma unroll
    for (int ks = 0; ks < 2; ks++)
      qf[rt][ks] = *(const short8*)(Qb + (size_t)(qrow0 + rt * 16 + lr) * HD + ks * 32 + lq * 8);

  // staging constants: both tiles are 64 rows x 64 elems (128 B row, 8 granules, swz3)
  const int srow = (w << 4) + (lane >> 3);  // rows srow, srow+8
  const int sgl = lane & 7;
  const int sb0 = (w << 4) << 6;
  const int sb1 = ((w << 4) + 8) << 6;

#define STAGE(tb, nb)                                                                  \
  {                                                                                    \
    const int r0 = srow, r1 = srow + 8;                                                \
    dma16(Kb + ((size_t)((tb) + r0) << 6) + ((sgl ^ (r0 & 7)) << 3), &Ks[nb][sb0]);    \
    dma16(Kb + ((size_t)((tb) + r1) << 6) + ((sgl ^ (r1 & 7)) << 3), &Ks[nb][sb1]);    \
    dma16(Vb + (size_t)r0 * SEQ + (tb) + ((sgl ^ (r0 & 7)) << 3), &VTs[nb][sb0]);      \
    dma16(Vb + (size_t)r1 * SEQ + (tb) + ((sgl ^ (r1 & 7)) << 3), &VTs[nb][sb1]);      \
  }

  const int nkt = qt + 1;
  STAGE(0, 0);

  floatx4 o[2][4];
#pragma unroll
  for (int rt = 0; rt < 2; rt++)
#pragma unroll
    for (int dt = 0; dt < 4; dt++) o[rt][dt] = (floatx4){0.f, 0.f, 0.f, 0.f};
  float ls[2] = {0.f, 0.f};

  const int idx0 = (lr + ((lq & 1) << 5)) << 2;  // bpermute byte indices
  const int idx1 = idx0 + 64;
  const bool hi = (lq >= 2);

  // LDS read offsets (element units)
  const int kfb0 = ((wb << 4) + lr) << 6;                  // + nt*2048
  const int kg0 = ((lq ^ (lr & 7)) << 3);                  // ks=0 granule
  const int kg1 = (((4 + lq) ^ (lr & 7)) << 3);            // ks=1
  const int vg = ((((lq & 2) << 1) + (wb << 1) + (lq & 1)) ^ (lr & 7)) << 3;

  for (int kt = 0; kt < nkt; kt++) {
    WAIT_VM(0);
    BARRIER();
    if (kt + 1 < nkt) STAGE((kt + 1) << 6, (kt + 1) & 1);

    const int kw0 = (kt << 6) + (wb << 4);  // wave's first key
    if (kw0 <= qrow0 + 31) {
      const __hip_bfloat16* Kc = Ks[kt & 1];
      const __hip_bfloat16* Vc = VTs[kt & 1];

      // K frags (shared across rt): row = nt*32 + wb*16 + lr
      short8 kf[2][2];  // [ks][nt]
#pragma unroll
      for (int nt = 0; nt < 2; nt++) {
        kf[0][nt] = *(const short8*)&Kc[(nt << 11) + kfb0 + kg0];
        kf[1][nt] = *(const short8*)&Kc[(nt << 11) + kfb0 + kg1];
      }
      // S^T = K Q^T
      floatx4 s[2][2];  // [rt][nt]
#pragma unroll
      for (int rt = 0; rt < 2; rt++)
#pragma unroll
        for (int nt = 0; nt < 2; nt++) s[rt][nt] = (floatx4){0.f, 0.f, 0.f, 0.f};
#pragma unroll
      for (int ks = 0; ks < 2; ks++)
#pragma unroll
        for (int nt = 0; nt < 2; nt++) {
          s[0][nt] = mfma_bf16(kf[ks][nt], qf[0][ks], s[0][nt]);
          s[1][nt] = mfma_bf16(kf[ks][nt], qf[1][ks], s[1][nt]);
        }

      // numerators (mask only near the diagonal), pack to bf16 pairs
      const bool need_mask = (kw0 + 47 > qrow0);
      int pkA[2][2], pkB[2][2];  // [rt][nt]
#pragma unroll
      for (int rt = 0; rt < 2; rt++) {
        const int q = qrow0 + rt * 16 + lr;
#pragma unroll
        for (int nt = 0; nt < 2; nt++) {
          const int kbase = (kt << 6) + (nt << 5) + (wb << 4) + (lq << 2);
          float x0 = s[rt][nt][0], x1 = s[rt][nt][1], x2 = s[rt][nt][2], x3 = s[rt][nt][3];
          if (need_mask) {
            x0 = (kbase + 0 <= q) ? x0 : -1e30f;
            x1 = (kbase + 1 <= q) ? x1 : -1e30f;
            x2 = (kbase + 2 <= q) ? x2 : -1e30f;
            x3 = (kbase + 3 <= q) ? x3 : -1e30f;
          }
          const float p0 = __builtin_amdgcn_exp2f(x0);
          const float p1 = __builtin_amdgcn_exp2f(x1);
          const float p2 = __builtin_amdgcn_exp2f(x2);
          const float p3 = __builtin_amdgcn_exp2f(x3);
          ls[rt] += (p0 + p1) + (p2 + p3);
          pkA[rt][nt] = pack2bf(p0, p1);
          pkB[rt][nt] = pack2bf(p2, p3);
        }
      }

      // P^T B-frags via bpermute; O^T += V^T P^T (single 32-key ks-step)
      short8 pf[2];
#pragma unroll
      for (int rt = 0; rt < 2; rt++) {
        int c0a = __builtin_amdgcn_ds_bpermute(idx0, pkA[rt][0]);
        int c0b = __builtin_amdgcn_ds_bpermute(idx0, pkA[rt][1]);
        int c1a = __builtin_amdgcn_ds_bpermute(idx0, pkB[rt][0]);
        int c1b = __builtin_amdgcn_ds_bpermute(idx0, pkB[rt][1]);
        int c2a = __builtin_amdgcn_ds_bpermute(idx1, pkA[rt][0]);
        int c2b = __builtin_amdgcn_ds_bpermute(idx1, pkA[rt][1]);
        int c3a = __builtin_amdgcn_ds_bpermute(idx1, pkB[rt][0]);
        int c3b = __builtin_amdgcn_ds_bpermute(idx1, pkB[rt][1]);
        intx4 bi;
        bi[0] = hi ? c0b : c0a;
        bi[1] = hi ? c1b : c1a;
        bi[2] = hi ? c2b : c2a;
        bi[3] = hi ? c3b : c3a;
        pf[rt] = __builtin_bit_cast(short8, bi);
      }
#pragma unroll
      for (int dt = 0; dt < 4; dt++) {
        short8 vf = *(const short8*)&Vc[(((dt << 4) + lr) << 6) + vg];
        o[0][dt] = mfma_bf16(vf, pf[0], o[0][dt]);
        o[1][dt] = mfma_bf16(vf, pf[1], o[1][dt]);
      }
    }
  }

  // ---- epilogue: merge wb partials via (now free) LDS buffers ----
  BARRIER();
  if (wb == 1) {
    float* d0 = (float*)&Ks[0][0];   // rt0 partials (8 KB)
    float* d1 = (float*)&Ks[1][0];   // rt1 partials (8 KB)
    float* dl = (float*)&VTs[0][0];  // l partials
    const int base = (wr << 10) + (lane << 4);
#pragma unroll
    for (int dt = 0; dt < 4; dt++) *(floatx4*)&d0[base + (dt << 2)] = o[0][dt];
#pragma unroll
    for (int dt = 0; dt < 4; dt++) *(floatx4*)&d1[base + (dt << 2)] = o[1][dt];
    dl[(wr << 7) + (lane << 1)] = ls[0];
    dl[(wr << 7) + (lane << 1) + 1] = ls[1];
    WAIT_LGKM();
  }
  BARRIER();
  if (wb == 0) {
    const float* d0 = (const float*)&Ks[0][0];
    const float* d1 = (const float*)&Ks[1][0];
    const float* dl = (const float*)&VTs[0][0];
    const int base = (wr << 10) + (lane << 4);
#pragma unroll
    for (int dt = 0; dt < 4; dt++) {
      o[0][dt] += *(const floatx4*)&d0[base + (dt << 2)];
      o[1][dt] += *(const floatx4*)&d1[base + (dt << 2)];
    }
    ls[0] += dl[(wr << 7) + (lane << 1)];
    ls[1] += dl[(wr << 7) + (lane << 1) + 1];
    float inv[2];
#pragma unroll
    for (int rt = 0; rt < 2; rt++) {
      float v = ls[rt];
      v += __shfl_xor(v, 16);
      v += __shfl_xor(v, 32);
      inv[rt] = 1.f / v;
    }
#pragma unroll
    for (int rt = 0; rt < 2; rt++) {
      const int row = qrow0 + rt * 16 + lr;
      __hip_bfloat16* cp = ctx + (size_t)b * SEQ * D_MODEL + (size_t)row * D_MODEL + h * HD;
#pragma unroll
      for (int dt = 0; dt < 4; dt++) {
        ushort4 pk;
        __hip_bfloat16* pp = (__hip_bfloat16*)&pk;
#pragma unroll
        for (int r = 0; r < 4; r++) pp[r] = __float2bfloat16(o[rt][dt][r] * inv[rt]);
        *(ushort4*)(cp + (dt << 4) + (lq << 2)) = pk;
      }
    }
  }
#undef STAGE
}

extern "C" void kernel_launch(void* const* d_in, const int* in_sizes, int n_in,
                              void* d_out, int out_size, void* d_ws, size_t ws_size,
                              hipStream_t stream) {
  const float* x  = (const float*)d_in[0];
  const float* Wq = (const float*)d_in[1];
  const float* bq = (const float*)d_in[2];
  const float* Wk = (const float*)d_in[3];
  const float* bk = (const float*)d_in[4];
  const float* Wv = (const float*)d_in[5];
  const float* bv = (const float*)d_in[6];
  const float* Wo = (const float*)d_in[7];
  const float* bo = (const float*)d_in[8];

  char* ws = (char*)d_ws;
  const size_t MB = 1u << 20;
  __hip_bfloat16* xb  = (__hip_bfloat16*)(ws + 0 * MB);   // 8 MB; reused as ctx after QKV GEMM
  __hip_bfloat16* wtq = (__hip_bfloat16*)(ws + 8 * MB);
  __hip_bfloat16* wtk = (__hip_bfloat16*)(ws + 10 * MB);
  __hip_bfloat16* wtv = (__hip_bfloat16*)(ws + 12 * MB);
  __hip_bfloat16* wto = (__hip_bfloat16*)(ws + 14 * MB);
  __hip_bfloat16* qb  = (__hip_bfloat16*)(ws + 16 * MB);
  __hip_bfloat16* kb  = (__hip_bfloat16*)(ws + 24 * MB);
  __hip_bfloat16* vt  = (__hip_bfloat16*)(ws + 32 * MB);
  __hip_bfloat16* ctx = xb;  // alias: x no longer needed after QKV projection

  prep_kernel<<<dim3(32, 32, 5), dim3(32, 8), 0, stream>>>(x, xb, Wq, Wk, Wv, Wo,
                                                           wtq, wtk, wtv, wto);
  gemm_kernel<0><<<dim3(8, 3, 32), 256, 0, stream>>>(xb, wtq, wtk, wtv, bq, bk, bv,
                                                     (void*)qb, (void*)kb, (void*)vt);
  attn_kernel<<<dim3(32, 32), 256, 0, stream>>>(qb, kb, vt, ctx);
  gemm_kernel<1><<<dim3(8, 1, 64), 256, 0, stream>>>(ctx, wto, wto, wto, bo, bo, bo,
                                                     d_out, d_out, d_out);
}